// Round 7
// baseline (1186.737 us; speedup 1.0000x reference)
//
#include <hip/hip_runtime.h>
#include <hip/hip_bf16.h>

#define NN 50000
#define NE 800000
#define DH 128
#define DE 16
#define DM 128
#define K1 273
#define EPB 32
#define NPB 32
#define M1S 136   // LDS row stride (bf16) for m1/m2/t tiles: 272B, 16B-aligned, banks ≡4 mod 32
#define NHS 264   // LDS row stride (bf16) for node h_in: 528B, 16B-aligned, banks ≡4 mod 32

typedef __attribute__((ext_vector_type(8))) short s16x8;
typedef __attribute__((ext_vector_type(4))) short s16x4;
typedef __attribute__((ext_vector_type(4))) float f32x4;

// Device-global scratch (no ws dependence). Rewritten every launch.
__device__ float g_msum[NN * DM];                    // 25.6 MB fp32 accumulator
__device__ __hip_bfloat16 g_P[NN * DM];              // h @ W_a^T, bf16 (12.8 MB)
__device__ __hip_bfloat16 g_Q[NN * DM];              // h @ W_b^T, bf16 (12.8 MB)
__device__ __hip_bfloat16 g_W1a[128 * 128];          // We1[:,0:128]
__device__ __hip_bfloat16 g_W1b[128 * 128];          // We1[:,128:256]
__device__ __hip_bfloat16 g_Wes[128 * 32];           // [ea(16) | radial | 0-pad] weights
__device__ __hip_bfloat16 g_W2b[128 * 128];
__device__ __hip_bfloat16 g_Wh1b[128 * 256];
__device__ __hip_bfloat16 g_Wh2b[128 * 128];

__device__ __forceinline__ __hip_bfloat16 f2bf(float v) { return __float2bfloat16(v); }
__device__ __forceinline__ float bf2f(__hip_bfloat16 v) { return __bfloat162float(v); }
__device__ __forceinline__ short bfbits(float f) {
    __hip_bfloat16 b = __float2bfloat16(f);
    return *reinterpret_cast<short*>(&b);
}
__device__ __forceinline__ float b2f(short s) {       // bf16 bits -> fp32 (exact)
    unsigned u = ((unsigned)(unsigned short)s) << 16;
    float f; __builtin_memcpy(&f, &u, 4); return f;
}
__device__ __forceinline__ float silu(float v) { return v / (1.f + __expf(-v)); }

__global__ __launch_bounds__(256) void zero_msum() {
    int i = blockIdx.x * 256 + threadIdx.x;     // grid 6250
    float4* p = (float4*)g_msum;
    if (i < NN * DM / 4) p[i] = make_float4(0.f, 0.f, 0.f, 0.f);
}

__global__ __launch_bounds__(256) void prep_weights(
    const float* __restrict__ We1, const float* __restrict__ We2,
    const float* __restrict__ Wh1, const float* __restrict__ Wh2) {
    int i = blockIdx.x * 256 + threadIdx.x;      // grid 128 -> 32768
    if (i < 16384) {
        int n = i >> 7, k = i & 127;
        g_W1a[i]  = f2bf(We1[n * K1 + k]);
        g_W1b[i]  = f2bf(We1[n * K1 + 128 + k]);
        g_W2b[i]  = f2bf(We2[i]);
        g_Wh2b[i] = f2bf(Wh2[i]);
    }
    if (i < 4096) {
        int n = i >> 5, k = i & 31;
        float v = (k < 16) ? We1[n * K1 + 257 + k] : (k == 16 ? We1[n * K1 + 256] : 0.f);
        g_Wes[i] = f2bf(v);
    }
    if (i < 32768) g_Wh1b[i] = f2bf(Wh1[i]);
}

// P/Q precompute: out[i][n] = sum_k h[i][k] * W[n][k], 50000x128, K=128.
// blockIdx.y: 0 -> (g_W1a, g_P), 1 -> (g_W1b, g_Q)
__global__ __launch_bounds__(256) void pq_kernel(const float* __restrict__ h) {
    __shared__ __align__(16) __hip_bfloat16 s_a[32 * M1S];
    const int tid = threadIdx.x, lane = tid & 63, wave = tid >> 6;
    const int n0 = blockIdx.x * 32;
    const __hip_bfloat16* W = blockIdx.y ? g_W1b : g_W1a;
    __hip_bfloat16* out = blockIdx.y ? g_Q : g_P;

    for (int i = tid; i < 32 * 16; i += 256) {
        int r = i >> 4, u = i & 15;
        int node = n0 + r; if (node >= NN) node = NN - 1;
        const float* hp = h + (size_t)node * DH + u * 8;
        float4 v0 = *(const float4*)(hp);
        float4 v1 = *(const float4*)(hp + 4);
        s16x8 t;
        t[0] = bfbits(v0.x); t[1] = bfbits(v0.y); t[2] = bfbits(v0.z); t[3] = bfbits(v0.w);
        t[4] = bfbits(v1.x); t[5] = bfbits(v1.y); t[6] = bfbits(v1.z); t[7] = bfbits(v1.w);
        *(s16x8*)(s_a + r * M1S + u * 8) = t;
    }
    __syncthreads();

    const int l15 = lane & 15, kq = (lane >> 4) * 8, rq = (lane >> 4) * 4, nb = wave * 32;
    f32x4 acc00 = {0,0,0,0}, acc01 = {0,0,0,0}, acc10 = {0,0,0,0}, acc11 = {0,0,0,0};
    #pragma unroll
    for (int k0 = 0; k0 < 128; k0 += 32) {
        s16x8 a0 = *(const s16x8*)(s_a + l15 * M1S + k0 + kq);
        s16x8 a1 = *(const s16x8*)(s_a + (16 + l15) * M1S + k0 + kq);
        s16x8 b0 = *(const s16x8*)(W + (size_t)(nb + l15) * 128 + k0 + kq);
        s16x8 b1 = *(const s16x8*)(W + (size_t)(nb + 16 + l15) * 128 + k0 + kq);
        acc00 = __builtin_amdgcn_mfma_f32_16x16x32_bf16(a0, b0, acc00, 0, 0, 0);
        acc01 = __builtin_amdgcn_mfma_f32_16x16x32_bf16(a0, b1, acc01, 0, 0, 0);
        acc10 = __builtin_amdgcn_mfma_f32_16x16x32_bf16(a1, b0, acc10, 0, 0, 0);
        acc11 = __builtin_amdgcn_mfma_f32_16x16x32_bf16(a1, b1, acc11, 0, 0, 0);
    }
    #pragma unroll
    for (int r = 0; r < 4; r++) {
        int m0 = n0 + rq + r, m1 = n0 + 16 + rq + r;
        if (m0 < NN) {
            out[(size_t)m0 * DM + nb + l15]      = f2bf(acc00[r]);
            out[(size_t)m0 * DM + nb + 16 + l15] = f2bf(acc01[r]);
        }
        if (m1 < NN) {
            out[(size_t)m1 * DM + nb + l15]      = f2bf(acc10[r]);
            out[(size_t)m1 * DM + nb + 16 + l15] = f2bf(acc11[r]);
        }
    }
}

// Edge kernel v2: layer1 via precomputed P/Q gather + K=32 MFMA for [ea|radial].
__global__ __launch_bounds__(256) void edge_kernel(
    const float* __restrict__ x,
    const float* __restrict__ ea,
    const float* __restrict__ be1,
    const float* __restrict__ be2,
    const float* __restrict__ Wa,
    const float* __restrict__ ba,
    const int* __restrict__ eidx)             // [2][NE] int32 planar
{
    // LDS plan (29184 B total -> 5 blocks/CU):
    //   [0,16896)      s_pre  fp32 [32][132]   (aliased by s_m2 bf16 [32][136] after layer1)
    //   [16896,25600)  s_m1   bf16 [32][136]
    //   [25600,27648)  s_eain bf16 [32][32]
    //   [27648,28672)  s_part fp32 [8][32]
    //   [28672,28800)  s_att  fp32 [32]
    //   [28800,28928)  s_rad  fp32 [32]
    //   [28928,29056)  s_row  int  [32]
    //   [29056,29184)  s_col  int  [32]
    __shared__ __align__(16) char smem[29184];
    float* s_pre = (float*)smem;
    __hip_bfloat16* s_m2 = (__hip_bfloat16*)smem;
    __hip_bfloat16* s_m1 = (__hip_bfloat16*)(smem + 16896);
    __hip_bfloat16* s_eain = (__hip_bfloat16*)(smem + 25600);
    float* s_part = (float*)(smem + 27648);
    float* s_att  = (float*)(smem + 28672);
    float* s_rad  = (float*)(smem + 28800);
    int*   s_row  = (int*)(smem + 28928);
    int*   s_col  = (int*)(smem + 29056);

    const int tid  = threadIdx.x;
    const int lane = tid & 63;
    const int wave = tid >> 6;
    const int e0   = blockIdx.x * EPB;

    if (tid < EPB) {
        int e = e0 + tid;
        int r = eidx[e], c = eidx[NE + e];
        s_row[tid] = r; s_col[tid] = c;
        float dx = x[r*3+0] - x[c*3+0];
        float dy = x[r*3+1] - x[c*3+1];
        float dz = x[r*3+2] - x[c*3+2];
        s_rad[tid] = sqrtf(dx*dx + dy*dy + dz*dz);
    }
    __syncthreads();

    // gather P[row]+Q[col] -> s_pre fp32 (one iteration per thread)
    {
        int e = tid >> 3, c = tid & 7;
        s16x8 pb = *(const s16x8*)(g_P + (size_t)s_row[e] * DM + c * 16);
        s16x8 qb = *(const s16x8*)(g_Q + (size_t)s_col[e] * DM + c * 16);
        float* dst = s_pre + e * 132 + c * 16;
        #pragma unroll
        for (int j = 0; j < 16; j++) dst[j] = b2f(pb[j]) + b2f(qb[j]);
    }
    // fill s_eain: [ea(16) | radial(1) | zeros]
    for (int i = tid; i < EPB * 32; i += 256) {
        int e = i >> 5, k = i & 31;
        float v = (k < 16) ? ea[(size_t)(e0 + e) * DE + k] : (k == 16 ? s_rad[e] : 0.f);
        s_eain[i] = f2bf(v);
    }
    __syncthreads();

    const int l15 = lane & 15;
    const int kq  = (lane >> 4) * 8;
    const int rq  = (lane >> 4) * 4;
    const int nb  = wave * 32;

    // layer 1: m1 = silu(P[row]+Q[col]+be1 + [ea|rad]@Wes^T), one K=32 step
    {
        float b0v = be1[nb + l15], b1v = be1[nb + 16 + l15];
        f32x4 acc00, acc01, acc10, acc11;
        #pragma unroll
        for (int r = 0; r < 4; r++) {
            acc00[r] = s_pre[(rq + r) * 132 + nb + l15] + b0v;
            acc01[r] = s_pre[(rq + r) * 132 + nb + 16 + l15] + b1v;
            acc10[r] = s_pre[(16 + rq + r) * 132 + nb + l15] + b0v;
            acc11[r] = s_pre[(16 + rq + r) * 132 + nb + 16 + l15] + b1v;
        }
        s16x8 a0 = *(const s16x8*)(s_eain + l15 * 32 + kq);
        s16x8 a1 = *(const s16x8*)(s_eain + (16 + l15) * 32 + kq);
        s16x8 b0 = *(const s16x8*)(g_Wes + (nb + l15) * 32 + kq);
        s16x8 b1 = *(const s16x8*)(g_Wes + (nb + 16 + l15) * 32 + kq);
        acc00 = __builtin_amdgcn_mfma_f32_16x16x32_bf16(a0, b0, acc00, 0, 0, 0);
        acc01 = __builtin_amdgcn_mfma_f32_16x16x32_bf16(a0, b1, acc01, 0, 0, 0);
        acc10 = __builtin_amdgcn_mfma_f32_16x16x32_bf16(a1, b0, acc10, 0, 0, 0);
        acc11 = __builtin_amdgcn_mfma_f32_16x16x32_bf16(a1, b1, acc11, 0, 0, 0);
        #pragma unroll
        for (int r = 0; r < 4; r++) {
            s_m1[(rq + r) * M1S + nb + l15]           = f2bf(silu(acc00[r]));
            s_m1[(rq + r) * M1S + nb + 16 + l15]      = f2bf(silu(acc01[r]));
            s_m1[(16 + rq + r) * M1S + nb + l15]      = f2bf(silu(acc10[r]));
            s_m1[(16 + rq + r) * M1S + nb + 16 + l15] = f2bf(silu(acc11[r]));
        }
    }
    __syncthreads();   // also: s_pre dead from here; s_m2 aliases it

    // layer 2: m2 = silu(m1 @ We2^T + be2), K=128
    {
        float bias0 = be2[nb + l15];
        float bias1 = be2[nb + 16 + l15];
        f32x4 acc00 = {bias0, bias0, bias0, bias0};
        f32x4 acc01 = {bias1, bias1, bias1, bias1};
        f32x4 acc10 = acc00, acc11 = acc01;
        #pragma unroll
        for (int k0 = 0; k0 < 128; k0 += 32) {
            s16x8 a0 = *(const s16x8*)(s_m1 + l15 * M1S + k0 + kq);
            s16x8 a1 = *(const s16x8*)(s_m1 + (16 + l15) * M1S + k0 + kq);
            s16x8 b0 = *(const s16x8*)(g_W2b + (size_t)(nb + l15) * 128 + k0 + kq);
            s16x8 b1 = *(const s16x8*)(g_W2b + (size_t)(nb + 16 + l15) * 128 + k0 + kq);
            acc00 = __builtin_amdgcn_mfma_f32_16x16x32_bf16(a0, b0, acc00, 0, 0, 0);
            acc01 = __builtin_amdgcn_mfma_f32_16x16x32_bf16(a0, b1, acc01, 0, 0, 0);
            acc10 = __builtin_amdgcn_mfma_f32_16x16x32_bf16(a1, b0, acc10, 0, 0, 0);
            acc11 = __builtin_amdgcn_mfma_f32_16x16x32_bf16(a1, b1, acc11, 0, 0, 0);
        }
        #pragma unroll
        for (int r = 0; r < 4; r++) {
            s_m2[(rq + r) * M1S + nb + l15]           = f2bf(silu(acc00[r]));
            s_m2[(rq + r) * M1S + nb + 16 + l15]      = f2bf(silu(acc01[r]));
            s_m2[(16 + rq + r) * M1S + nb + l15]      = f2bf(silu(acc10[r]));
            s_m2[(16 + rq + r) * M1S + nb + 16 + l15] = f2bf(silu(acc11[r]));
        }
    }
    __syncthreads();

    // attention gate: att = sigmoid(m2 @ Wa^T + ba)
    {
        int e = tid & 31, part = tid >> 5;
        float p = 0.f;
        #pragma unroll
        for (int j = 0; j < 16; j++) {
            int d = part * 16 + j;
            p += bf2f(s_m2[e * M1S + d]) * Wa[d];
        }
        s_part[part * 32 + e] = p;
    }
    __syncthreads();
    if (tid < 32) {
        float s = ba[0];
        #pragma unroll
        for (int p = 0; p < 8; p++) s += s_part[p * 32 + tid];
        s_att[tid] = 1.f / (1.f + __expf(-s));
    }
    __syncthreads();

    // scatter: msum[row[e]] += m2[e] * att[e]
    {
        int e = tid >> 3, dg = tid & 7;
        int node = s_row[e];
        float a = s_att[e];
        float* base = g_msum + (size_t)node * DM;
        #pragma unroll
        for (int j = 0; j < 16; j++) {
            int d = j * 8 + dg;
            atomicAdd(base + d, bf2f(s_m2[e * M1S + d]) * a);
        }
    }
}

__global__ __launch_bounds__(256) void node_kernel(
    const float* __restrict__ h,
    const float* __restrict__ bh1,
    const float* __restrict__ bh2,
    float* __restrict__ out)
{
    __shared__ __align__(16) __hip_bfloat16 s_hin[NPB * NHS];
    __shared__ __align__(16) __hip_bfloat16 s_t[NPB * M1S];

    const int tid  = threadIdx.x;
    const int lane = tid & 63;
    const int wave = tid >> 6;
    const int n0   = blockIdx.x * NPB;

    for (int i = tid; i < 32 * 16; i += 256) {
        int r = i >> 4, u = i & 15;
        int node = n0 + r; if (node >= NN) node = NN - 1;
        const float* hp = h + (size_t)node * DH + u * 8;
        float4 v0 = *(const float4*)(hp);
        float4 v1 = *(const float4*)(hp + 4);
        s16x8 t;
        t[0] = bfbits(v0.x); t[1] = bfbits(v0.y); t[2] = bfbits(v0.z); t[3] = bfbits(v0.w);
        t[4] = bfbits(v1.x); t[5] = bfbits(v1.y); t[6] = bfbits(v1.z); t[7] = bfbits(v1.w);
        *(s16x8*)(s_hin + r * NHS + u * 8) = t;
    }
    for (int i = tid; i < 32 * 32; i += 256) {
        int r = i >> 5, u = i & 31;
        int node = n0 + r; if (node >= NN) node = NN - 1;
        float4 v = *(const float4*)(g_msum + (size_t)node * DM + u * 4);
        s16x4 t;
        t[0] = bfbits(v.x); t[1] = bfbits(v.y); t[2] = bfbits(v.z); t[3] = bfbits(v.w);
        *(s16x4*)(s_hin + r * NHS + 128 + u * 4) = t;
    }
    __syncthreads();

    const int l15 = lane & 15;
    const int kq  = (lane >> 4) * 8;
    const int rq  = (lane >> 4) * 4;
    const int nb  = wave * 32;

    // layer 1: t = silu(h_in @ Wh1^T + bh1), K=256
    {
        float bias0 = bh1[nb + l15];
        float bias1 = bh1[nb + 16 + l15];
        f32x4 acc00 = {bias0, bias0, bias0, bias0};
        f32x4 acc01 = {bias1, bias1, bias1, bias1};
        f32x4 acc10 = acc00, acc11 = acc01;
        #pragma unroll
        for (int k0 = 0; k0 < 256; k0 += 32) {
            s16x8 a0 = *(const s16x8*)(s_hin + l15 * NHS + k0 + kq);
            s16x8 a1 = *(const s16x8*)(s_hin + (16 + l15) * NHS + k0 + kq);
            s16x8 b0 = *(const s16x8*)(g_Wh1b + (size_t)(nb + l15) * 256 + k0 + kq);
            s16x8 b1 = *(const s16x8*)(g_Wh1b + (size_t)(nb + 16 + l15) * 256 + k0 + kq);
            acc00 = __builtin_amdgcn_mfma_f32_16x16x32_bf16(a0, b0, acc00, 0, 0, 0);
            acc01 = __builtin_amdgcn_mfma_f32_16x16x32_bf16(a0, b1, acc01, 0, 0, 0);
            acc10 = __builtin_amdgcn_mfma_f32_16x16x32_bf16(a1, b0, acc10, 0, 0, 0);
            acc11 = __builtin_amdgcn_mfma_f32_16x16x32_bf16(a1, b1, acc11, 0, 0, 0);
        }
        #pragma unroll
        for (int r = 0; r < 4; r++) {
            s_t[(rq + r) * M1S + nb + l15]           = f2bf(silu(acc00[r]));
            s_t[(rq + r) * M1S + nb + 16 + l15]      = f2bf(silu(acc01[r]));
            s_t[(16 + rq + r) * M1S + nb + l15]      = f2bf(silu(acc10[r]));
            s_t[(16 + rq + r) * M1S + nb + 16 + l15] = f2bf(silu(acc11[r]));
        }
    }
    __syncthreads();

    // layer 2 + residual: out = h + t @ Wh2^T + bh2, K=128 (fp32 store)
    {
        float bias0 = bh2[nb + l15];
        float bias1 = bh2[nb + 16 + l15];
        f32x4 acc00 = {bias0, bias0, bias0, bias0};
        f32x4 acc01 = {bias1, bias1, bias1, bias1};
        f32x4 acc10 = acc00, acc11 = acc01;
        #pragma unroll
        for (int k0 = 0; k0 < 128; k0 += 32) {
            s16x8 a0 = *(const s16x8*)(s_t + l15 * M1S + k0 + kq);
            s16x8 a1 = *(const s16x8*)(s_t + (16 + l15) * M1S + k0 + kq);
            s16x8 b0 = *(const s16x8*)(g_Wh2b + (size_t)(nb + l15) * 128 + k0 + kq);
            s16x8 b1 = *(const s16x8*)(g_Wh2b + (size_t)(nb + 16 + l15) * 128 + k0 + kq);
            acc00 = __builtin_amdgcn_mfma_f32_16x16x32_bf16(a0, b0, acc00, 0, 0, 0);
            acc01 = __builtin_amdgcn_mfma_f32_16x16x32_bf16(a0, b1, acc01, 0, 0, 0);
            acc10 = __builtin_amdgcn_mfma_f32_16x16x32_bf16(a1, b0, acc10, 0, 0, 0);
            acc11 = __builtin_amdgcn_mfma_f32_16x16x32_bf16(a1, b1, acc11, 0, 0, 0);
        }
        #pragma unroll
        for (int r = 0; r < 4; r++) {
            int n00 = n0 + rq + r;
            int n16 = n0 + 16 + rq + r;
            int d0 = nb + l15, d1 = nb + 16 + l15;
            if (n00 < NN) {
                out[(size_t)n00 * DH + d0] = acc00[r] + h[(size_t)n00 * DH + d0];
                out[(size_t)n00 * DH + d1] = acc01[r] + h[(size_t)n00 * DH + d1];
            }
            if (n16 < NN) {
                out[(size_t)n16 * DH + d0] = acc10[r] + h[(size_t)n16 * DH + d0];
                out[(size_t)n16 * DH + d1] = acc11[r] + h[(size_t)n16 * DH + d1];
            }
        }
    }
}

extern "C" void kernel_launch(void* const* d_in, const int* in_sizes, int n_in,
                              void* d_out, int out_size, void* d_ws, size_t ws_size,
                              hipStream_t stream) {
    const float* x   = (const float*)d_in[0];
    const float* h   = (const float*)d_in[1];
    const float* ea  = (const float*)d_in[2];
    const float* We1 = (const float*)d_in[3];
    const float* be1 = (const float*)d_in[4];
    const float* We2 = (const float*)d_in[5];
    const float* be2 = (const float*)d_in[6];
    const float* Wh1 = (const float*)d_in[7];
    const float* bh1 = (const float*)d_in[8];
    const float* Wh2 = (const float*)d_in[9];
    const float* bh2 = (const float*)d_in[10];
    const float* Wa  = (const float*)d_in[11];
    const float* ba  = (const float*)d_in[12];
    const int* eidx  = (const int*)d_in[13];   // int32 planar [rows | cols]

    zero_msum<<<6250, 256, 0, stream>>>();
    prep_weights<<<128, 256, 0, stream>>>(We1, We2, Wh1, Wh2);
    pq_kernel<<<dim3((NN + 31) / 32, 2), 256, 0, stream>>>(h);
    edge_kernel<<<NE / EPB, 256, 0, stream>>>(x, ea, be1, be2, Wa, ba, eidx);
    node_kernel<<<(NN + NPB - 1) / NPB, 256, 0, stream>>>(h, bh1, bh2, (float*)d_out);
}

// Round 8
// 814.214 us; speedup vs baseline: 1.4575x; 1.4575x over previous
//
#include <hip/hip_runtime.h>
#include <hip/hip_bf16.h>

#define NN 50000
#define NE 800000
#define DH 128
#define DE 16
#define DM 128
#define K1 273
#define NPB 32
#define M1S 136   // LDS row stride (bf16): 272B, 16B-aligned, banks ≡4 mod 32
#define NHS 264   // LDS row stride (bf16) for node h_in

typedef __attribute__((ext_vector_type(8))) short s16x8;
typedef __attribute__((ext_vector_type(4))) short s16x4;
typedef __attribute__((ext_vector_type(4))) float f32x4;

// Device-global scratch (no ws dependence). Fully rewritten every launch.
__device__ float g_msum[NN * DM];                    // 25.6 MB fp32
__device__ __hip_bfloat16 g_P[NN * DM];              // h @ W_a^T
__device__ __hip_bfloat16 g_Q[NN * DM];              // h @ W_b^T
__device__ __hip_bfloat16 g_W1a[128 * 128];
__device__ __hip_bfloat16 g_W1b[128 * 128];
__device__ __hip_bfloat16 g_Wes[128 * 32];           // [ea(16)|radial|pad] weights
__device__ __hip_bfloat16 g_W2b[128 * 128];
__device__ __hip_bfloat16 g_Wh1b[128 * 256];
__device__ __hip_bfloat16 g_Wh2b[128 * 128];
// CSR build
__device__ int g_hist[NN];
__device__ int g_off[NN];
__device__ int g_cur[NN];
__device__ int g_bsum[256];
__device__ int g_csr[NE];

__device__ __forceinline__ __hip_bfloat16 f2bf(float v) { return __float2bfloat16(v); }
__device__ __forceinline__ float bf2f(__hip_bfloat16 v) { return __bfloat162float(v); }
__device__ __forceinline__ short bfbits(float f) {
    __hip_bfloat16 b = __float2bfloat16(f);
    return *reinterpret_cast<short*>(&b);
}
__device__ __forceinline__ float b2f(short s) {
    unsigned u = ((unsigned)(unsigned short)s) << 16;
    float f; __builtin_memcpy(&f, &u, 4); return f;
}
__device__ __forceinline__ float silu(float v) { return v / (1.f + __expf(-v)); }

__global__ __launch_bounds__(256) void prep_weights(
    const float* __restrict__ We1, const float* __restrict__ We2,
    const float* __restrict__ Wh1, const float* __restrict__ Wh2) {
    int i = blockIdx.x * 256 + threadIdx.x;      // grid 128 -> 32768
    if (i < 16384) {
        int n = i >> 7, k = i & 127;
        g_W1a[i]  = f2bf(We1[n * K1 + k]);
        g_W1b[i]  = f2bf(We1[n * K1 + 128 + k]);
        g_W2b[i]  = f2bf(We2[i]);
        g_Wh2b[i] = f2bf(Wh2[i]);
    }
    if (i < 4096) {
        int n = i >> 5, k = i & 31;
        float v = (k < 16) ? We1[n * K1 + 257 + k] : (k == 16 ? We1[n * K1 + 256] : 0.f);
        g_Wes[i] = f2bf(v);
    }
    if (i < 32768) g_Wh1b[i] = f2bf(Wh1[i]);
}

// ---------- CSR build ----------
__global__ __launch_bounds__(256) void hist_zero() {
    int i = blockIdx.x * 256 + threadIdx.x;
    if (i < NN) g_hist[i] = 0;
}
__global__ __launch_bounds__(256) void hist_count(const int* __restrict__ eidx) {
    int e = blockIdx.x * 256 + threadIdx.x;
    if (e < NE) atomicAdd(&g_hist[eidx[e]], 1);
}
__global__ __launch_bounds__(256) void scan1() {
    __shared__ int s[256];
    int tid = threadIdx.x, i = blockIdx.x * 256 + tid;
    int v = (i < NN) ? g_hist[i] : 0;
    s[tid] = v; __syncthreads();
    for (int o = 1; o < 256; o <<= 1) {
        int t = (tid >= o) ? s[tid - o] : 0;
        __syncthreads();
        s[tid] += t;
        __syncthreads();
    }
    if (i < NN) g_off[i] = s[tid] - v;
    if (tid == 255) g_bsum[blockIdx.x] = s[tid];
}
__global__ __launch_bounds__(256) void scan2(int nblk) {
    __shared__ int s[256];
    int tid = threadIdx.x;
    int v = (tid < nblk) ? g_bsum[tid] : 0;
    s[tid] = v; __syncthreads();
    for (int o = 1; o < 256; o <<= 1) {
        int t = (tid >= o) ? s[tid - o] : 0;
        __syncthreads();
        s[tid] += t;
        __syncthreads();
    }
    g_bsum[tid] = s[tid] - v;
}
__global__ __launch_bounds__(256) void scan3() {
    int i = blockIdx.x * 256 + threadIdx.x;
    if (i < NN) {
        int o = g_off[i] + g_bsum[blockIdx.x];
        g_off[i] = o;
        g_cur[i] = o;
    }
}
__global__ __launch_bounds__(256) void csr_fill(const int* __restrict__ eidx) {
    int e = blockIdx.x * 256 + threadIdx.x;
    if (e < NE) {
        int r = eidx[e];
        int pos = atomicAdd(&g_cur[r], 1);
        g_csr[pos] = e;
    }
}

// ---------- P/Q precompute ----------
__global__ __launch_bounds__(256) void pq_kernel(const float* __restrict__ h) {
    __shared__ __align__(16) __hip_bfloat16 s_a[32 * M1S];
    const int tid = threadIdx.x, lane = tid & 63, wave = tid >> 6;
    const int n0 = blockIdx.x * 32;
    const __hip_bfloat16* W = blockIdx.y ? g_W1b : g_W1a;
    __hip_bfloat16* out = blockIdx.y ? g_Q : g_P;

    for (int i = tid; i < 32 * 16; i += 256) {
        int r = i >> 4, u = i & 15;
        int node = n0 + r; if (node >= NN) node = NN - 1;
        const float* hp = h + (size_t)node * DH + u * 8;
        float4 v0 = *(const float4*)(hp);
        float4 v1 = *(const float4*)(hp + 4);
        s16x8 t;
        t[0] = bfbits(v0.x); t[1] = bfbits(v0.y); t[2] = bfbits(v0.z); t[3] = bfbits(v0.w);
        t[4] = bfbits(v1.x); t[5] = bfbits(v1.y); t[6] = bfbits(v1.z); t[7] = bfbits(v1.w);
        *(s16x8*)(s_a + r * M1S + u * 8) = t;
    }
    __syncthreads();

    const int l15 = lane & 15, kq = (lane >> 4) * 8, rq = (lane >> 4) * 4, nb = wave * 32;
    f32x4 acc00 = {0,0,0,0}, acc01 = {0,0,0,0}, acc10 = {0,0,0,0}, acc11 = {0,0,0,0};
    #pragma unroll
    for (int k0 = 0; k0 < 128; k0 += 32) {
        s16x8 a0 = *(const s16x8*)(s_a + l15 * M1S + k0 + kq);
        s16x8 a1 = *(const s16x8*)(s_a + (16 + l15) * M1S + k0 + kq);
        s16x8 b0 = *(const s16x8*)(W + (size_t)(nb + l15) * 128 + k0 + kq);
        s16x8 b1 = *(const s16x8*)(W + (size_t)(nb + 16 + l15) * 128 + k0 + kq);
        acc00 = __builtin_amdgcn_mfma_f32_16x16x32_bf16(a0, b0, acc00, 0, 0, 0);
        acc01 = __builtin_amdgcn_mfma_f32_16x16x32_bf16(a0, b1, acc01, 0, 0, 0);
        acc10 = __builtin_amdgcn_mfma_f32_16x16x32_bf16(a1, b0, acc10, 0, 0, 0);
        acc11 = __builtin_amdgcn_mfma_f32_16x16x32_bf16(a1, b1, acc11, 0, 0, 0);
    }
    #pragma unroll
    for (int r = 0; r < 4; r++) {
        int m0 = n0 + rq + r, m1 = n0 + 16 + rq + r;
        if (m0 < NN) {
            out[(size_t)m0 * DM + nb + l15]      = f2bf(acc00[r]);
            out[(size_t)m0 * DM + nb + 16 + l15] = f2bf(acc01[r]);
        }
        if (m1 < NN) {
            out[(size_t)m1 * DM + nb + l15]      = f2bf(acc10[r]);
            out[(size_t)m1 * DM + nb + 16 + l15] = f2bf(acc11[r]);
        }
    }
}

// ---------- node-major edge kernel: one block per destination node ----------
__global__ __launch_bounds__(256) void edge_agg(
    const float* __restrict__ x,
    const float* __restrict__ ea,
    const float* __restrict__ be1,
    const float* __restrict__ be2,
    const float* __restrict__ Wa,
    const float* __restrict__ ba,
    const int* __restrict__ eidx)
{
    // LDS plan (29184 B -> 5 blocks/CU):
    //   [0,16896)      s_pre fp32 [32][132]  (aliased by s_m2 bf16 [32][136])
    //   [16896,25600)  s_m1  bf16 [32][136]
    //   [25600,27648)  s_eain bf16 [32][32]
    //   [27648,28672)  s_part fp32 [8][32]
    //   [28672,28800)  s_att fp32 [32]
    //   [28800,28928)  s_rad fp32 [32]
    //   [28928,29056)  s_col int [32]
    //   [29056,29184)  s_eid int [32]
    __shared__ __align__(16) char smem[29184];
    float* s_pre = (float*)smem;
    __hip_bfloat16* s_m2 = (__hip_bfloat16*)smem;
    __hip_bfloat16* s_m1 = (__hip_bfloat16*)(smem + 16896);
    __hip_bfloat16* s_eain = (__hip_bfloat16*)(smem + 25600);
    float* s_part = (float*)(smem + 27648);
    float* s_att  = (float*)(smem + 28672);
    float* s_rad  = (float*)(smem + 28800);
    int*   s_col  = (int*)(smem + 28928);
    int*   s_eid  = (int*)(smem + 29056);

    const int tid  = threadIdx.x;
    const int lane = tid & 63;
    const int wave = tid >> 6;
    const int n    = blockIdx.x;

    const int base = g_off[n];
    const int cnt  = g_hist[n];

    const int l15 = lane & 15;
    const int kq  = (lane >> 4) * 8;
    const int rq  = (lane >> 4) * 4;
    const int nb  = wave * 32;

    float accd = 0.f;    // thread tid<128 owns output dim tid

    for (int t0 = 0; t0 < cnt; t0 += 32) {
        int nv = cnt - t0; if (nv > 32) nv = 32;

        if (tid < 32) {
            int i = tid;
            bool valid = i < nv;
            int eid = valid ? g_csr[base + t0 + i] : -1;
            int col = valid ? eidx[NE + eid] : n;
            s_eid[i] = eid;
            s_col[i] = col;
            float dx = x[n*3+0] - x[col*3+0];
            float dy = x[n*3+1] - x[col*3+1];
            float dz = x[n*3+2] - x[col*3+2];
            s_rad[i] = valid ? sqrtf(dx*dx + dy*dy + dz*dz) : 0.f;
        }
        __syncthreads();

        // gather P[n] + Q[col] -> s_pre fp32
        {
            int e = tid >> 3, c = tid & 7;
            s16x8 pb = *(const s16x8*)(g_P + (size_t)n * DM + c * 16);
            s16x8 qb = *(const s16x8*)(g_Q + (size_t)s_col[e] * DM + c * 16);
            float* dst = s_pre + e * 132 + c * 16;
            #pragma unroll
            for (int j = 0; j < 16; j++) dst[j] = b2f(pb[j]) + b2f(qb[j]);
        }
        // s_eain: [ea(16) | radial | zeros]
        for (int i = tid; i < 32 * 32; i += 256) {
            int e = i >> 5, k = i & 31;
            int eid = s_eid[e];
            float v = (k < 16) ? (eid >= 0 ? ea[(size_t)eid * DE + k] : 0.f)
                               : (k == 16 ? s_rad[e] : 0.f);
            s_eain[i] = f2bf(v);
        }
        __syncthreads();

        // layer 1: m1 = silu(P+Q+be1 + [ea|rad]@Wes^T), one K=32 MFMA step
        {
            float b0v = be1[nb + l15], b1v = be1[nb + 16 + l15];
            f32x4 acc00, acc01, acc10, acc11;
            #pragma unroll
            for (int r = 0; r < 4; r++) {
                acc00[r] = s_pre[(rq + r) * 132 + nb + l15] + b0v;
                acc01[r] = s_pre[(rq + r) * 132 + nb + 16 + l15] + b1v;
                acc10[r] = s_pre[(16 + rq + r) * 132 + nb + l15] + b0v;
                acc11[r] = s_pre[(16 + rq + r) * 132 + nb + 16 + l15] + b1v;
            }
            s16x8 a0 = *(const s16x8*)(s_eain + l15 * 32 + kq);
            s16x8 a1 = *(const s16x8*)(s_eain + (16 + l15) * 32 + kq);
            s16x8 b0 = *(const s16x8*)(g_Wes + (nb + l15) * 32 + kq);
            s16x8 b1 = *(const s16x8*)(g_Wes + (nb + 16 + l15) * 32 + kq);
            acc00 = __builtin_amdgcn_mfma_f32_16x16x32_bf16(a0, b0, acc00, 0, 0, 0);
            acc01 = __builtin_amdgcn_mfma_f32_16x16x32_bf16(a0, b1, acc01, 0, 0, 0);
            acc10 = __builtin_amdgcn_mfma_f32_16x16x32_bf16(a1, b0, acc10, 0, 0, 0);
            acc11 = __builtin_amdgcn_mfma_f32_16x16x32_bf16(a1, b1, acc11, 0, 0, 0);
            #pragma unroll
            for (int r = 0; r < 4; r++) {
                s_m1[(rq + r) * M1S + nb + l15]           = f2bf(silu(acc00[r]));
                s_m1[(rq + r) * M1S + nb + 16 + l15]      = f2bf(silu(acc01[r]));
                s_m1[(16 + rq + r) * M1S + nb + l15]      = f2bf(silu(acc10[r]));
                s_m1[(16 + rq + r) * M1S + nb + 16 + l15] = f2bf(silu(acc11[r]));
            }
        }
        __syncthreads();   // s_pre dead; s_m2 aliases it

        // layer 2: m2 = silu(m1 @ We2^T + be2), K=128
        {
            float bias0 = be2[nb + l15];
            float bias1 = be2[nb + 16 + l15];
            f32x4 acc00 = {bias0, bias0, bias0, bias0};
            f32x4 acc01 = {bias1, bias1, bias1, bias1};
            f32x4 acc10 = acc00, acc11 = acc01;
            #pragma unroll
            for (int k0 = 0; k0 < 128; k0 += 32) {
                s16x8 a0 = *(const s16x8*)(s_m1 + l15 * M1S + k0 + kq);
                s16x8 a1 = *(const s16x8*)(s_m1 + (16 + l15) * M1S + k0 + kq);
                s16x8 b0 = *(const s16x8*)(g_W2b + (size_t)(nb + l15) * 128 + k0 + kq);
                s16x8 b1 = *(const s16x8*)(g_W2b + (size_t)(nb + 16 + l15) * 128 + k0 + kq);
                acc00 = __builtin_amdgcn_mfma_f32_16x16x32_bf16(a0, b0, acc00, 0, 0, 0);
                acc01 = __builtin_amdgcn_mfma_f32_16x16x32_bf16(a0, b1, acc01, 0, 0, 0);
                acc10 = __builtin_amdgcn_mfma_f32_16x16x32_bf16(a1, b0, acc10, 0, 0, 0);
                acc11 = __builtin_amdgcn_mfma_f32_16x16x32_bf16(a1, b1, acc11, 0, 0, 0);
            }
            #pragma unroll
            for (int r = 0; r < 4; r++) {
                s_m2[(rq + r) * M1S + nb + l15]           = f2bf(silu(acc00[r]));
                s_m2[(rq + r) * M1S + nb + 16 + l15]      = f2bf(silu(acc01[r]));
                s_m2[(16 + rq + r) * M1S + nb + l15]      = f2bf(silu(acc10[r]));
                s_m2[(16 + rq + r) * M1S + nb + 16 + l15] = f2bf(silu(acc11[r]));
            }
        }
        __syncthreads();

        // attention gate (masked for invalid slots)
        {
            int e = tid & 31, part = tid >> 5;
            float p = 0.f;
            #pragma unroll
            for (int j = 0; j < 16; j++) {
                int d = part * 16 + j;
                p += bf2f(s_m2[e * M1S + d]) * Wa[d];
            }
            s_part[part * 32 + e] = p;
        }
        __syncthreads();
        if (tid < 32) {
            float s = ba[0];
            #pragma unroll
            for (int p = 0; p < 8; p++) s += s_part[p * 32 + tid];
            s_att[tid] = (tid < nv) ? 1.f / (1.f + __expf(-s)) : 0.f;
        }
        __syncthreads();

        // accumulate in registers (exact fp32, no atomics)
        if (tid < 128) {
            int d = tid;
            float a = 0.f;
            #pragma unroll
            for (int e = 0; e < 32; e++)
                a += bf2f(s_m2[e * M1S + d]) * s_att[e];
            accd += a;
        }
        __syncthreads();   // protect s_m2/s_att before next tile's writes
    }

    if (tid < 128) g_msum[(size_t)n * DM + tid] = accd;
}

__global__ __launch_bounds__(256) void node_kernel(
    const float* __restrict__ h,
    const float* __restrict__ bh1,
    const float* __restrict__ bh2,
    float* __restrict__ out)
{
    __shared__ __align__(16) __hip_bfloat16 s_hin[NPB * NHS];
    __shared__ __align__(16) __hip_bfloat16 s_t[NPB * M1S];

    const int tid  = threadIdx.x;
    const int lane = tid & 63;
    const int wave = tid >> 6;
    const int n0   = blockIdx.x * NPB;

    for (int i = tid; i < 32 * 16; i += 256) {
        int r = i >> 4, u = i & 15;
        int node = n0 + r; if (node >= NN) node = NN - 1;
        const float* hp = h + (size_t)node * DH + u * 8;
        float4 v0 = *(const float4*)(hp);
        float4 v1 = *(const float4*)(hp + 4);
        s16x8 t;
        t[0] = bfbits(v0.x); t[1] = bfbits(v0.y); t[2] = bfbits(v0.z); t[3] = bfbits(v0.w);
        t[4] = bfbits(v1.x); t[5] = bfbits(v1.y); t[6] = bfbits(v1.z); t[7] = bfbits(v1.w);
        *(s16x8*)(s_hin + r * NHS + u * 8) = t;
    }
    for (int i = tid; i < 32 * 32; i += 256) {
        int r = i >> 5, u = i & 31;
        int node = n0 + r; if (node >= NN) node = NN - 1;
        float4 v = *(const float4*)(g_msum + (size_t)node * DM + u * 4);
        s16x4 t;
        t[0] = bfbits(v.x); t[1] = bfbits(v.y); t[2] = bfbits(v.z); t[3] = bfbits(v.w);
        *(s16x4*)(s_hin + r * NHS + 128 + u * 4) = t;
    }
    __syncthreads();

    const int l15 = lane & 15;
    const int kq  = (lane >> 4) * 8;
    const int rq  = (lane >> 4) * 4;
    const int nb  = wave * 32;

    {
        float bias0 = bh1[nb + l15];
        float bias1 = bh1[nb + 16 + l15];
        f32x4 acc00 = {bias0, bias0, bias0, bias0};
        f32x4 acc01 = {bias1, bias1, bias1, bias1};
        f32x4 acc10 = acc00, acc11 = acc01;
        #pragma unroll
        for (int k0 = 0; k0 < 256; k0 += 32) {
            s16x8 a0 = *(const s16x8*)(s_hin + l15 * NHS + k0 + kq);
            s16x8 a1 = *(const s16x8*)(s_hin + (16 + l15) * NHS + k0 + kq);
            s16x8 b0 = *(const s16x8*)(g_Wh1b + (size_t)(nb + l15) * 256 + k0 + kq);
            s16x8 b1 = *(const s16x8*)(g_Wh1b + (size_t)(nb + 16 + l15) * 256 + k0 + kq);
            acc00 = __builtin_amdgcn_mfma_f32_16x16x32_bf16(a0, b0, acc00, 0, 0, 0);
            acc01 = __builtin_amdgcn_mfma_f32_16x16x32_bf16(a0, b1, acc01, 0, 0, 0);
            acc10 = __builtin_amdgcn_mfma_f32_16x16x32_bf16(a1, b0, acc10, 0, 0, 0);
            acc11 = __builtin_amdgcn_mfma_f32_16x16x32_bf16(a1, b1, acc11, 0, 0, 0);
        }
        #pragma unroll
        for (int r = 0; r < 4; r++) {
            s_t[(rq + r) * M1S + nb + l15]           = f2bf(silu(acc00[r]));
            s_t[(rq + r) * M1S + nb + 16 + l15]      = f2bf(silu(acc01[r]));
            s_t[(16 + rq + r) * M1S + nb + l15]      = f2bf(silu(acc10[r]));
            s_t[(16 + rq + r) * M1S + nb + 16 + l15] = f2bf(silu(acc11[r]));
        }
    }
    __syncthreads();

    {
        float bias0 = bh2[nb + l15];
        float bias1 = bh2[nb + 16 + l15];
        f32x4 acc00 = {bias0, bias0, bias0, bias0};
        f32x4 acc01 = {bias1, bias1, bias1, bias1};
        f32x4 acc10 = acc00, acc11 = acc01;
        #pragma unroll
        for (int k0 = 0; k0 < 128; k0 += 32) {
            s16x8 a0 = *(const s16x8*)(s_t + l15 * M1S + k0 + kq);
            s16x8 a1 = *(const s16x8*)(s_t + (16 + l15) * M1S + k0 + kq);
            s16x8 b0 = *(const s16x8*)(g_Wh2b + (size_t)(nb + l15) * 128 + k0 + kq);
            s16x8 b1 = *(const s16x8*)(g_Wh2b + (size_t)(nb + 16 + l15) * 128 + k0 + kq);
            acc00 = __builtin_amdgcn_mfma_f32_16x16x32_bf16(a0, b0, acc00, 0, 0, 0);
            acc01 = __builtin_amdgcn_mfma_f32_16x16x32_bf16(a0, b1, acc01, 0, 0, 0);
            acc10 = __builtin_amdgcn_mfma_f32_16x16x32_bf16(a1, b0, acc10, 0, 0, 0);
            acc11 = __builtin_amdgcn_mfma_f32_16x16x32_bf16(a1, b1, acc11, 0, 0, 0);
        }
        #pragma unroll
        for (int r = 0; r < 4; r++) {
            int n00 = n0 + rq + r;
            int n16 = n0 + 16 + rq + r;
            int d0 = nb + l15, d1 = nb + 16 + l15;
            if (n00 < NN) {
                out[(size_t)n00 * DH + d0] = acc00[r] + h[(size_t)n00 * DH + d0];
                out[(size_t)n00 * DH + d1] = acc01[r] + h[(size_t)n00 * DH + d1];
            }
            if (n16 < NN) {
                out[(size_t)n16 * DH + d0] = acc10[r] + h[(size_t)n16 * DH + d0];
                out[(size_t)n16 * DH + d1] = acc11[r] + h[(size_t)n16 * DH + d1];
            }
        }
    }
}

extern "C" void kernel_launch(void* const* d_in, const int* in_sizes, int n_in,
                              void* d_out, int out_size, void* d_ws, size_t ws_size,
                              hipStream_t stream) {
    const float* x   = (const float*)d_in[0];
    const float* h   = (const float*)d_in[1];
    const float* ea  = (const float*)d_in[2];
    const float* We1 = (const float*)d_in[3];
    const float* be1 = (const float*)d_in[4];
    const float* We2 = (const float*)d_in[5];
    const float* be2 = (const float*)d_in[6];
    const float* Wh1 = (const float*)d_in[7];
    const float* bh1 = (const float*)d_in[8];
    const float* Wh2 = (const float*)d_in[9];
    const float* bh2 = (const float*)d_in[10];
    const float* Wa  = (const float*)d_in[11];
    const float* ba  = (const float*)d_in[12];
    const int* eidx  = (const int*)d_in[13];   // int32 planar [rows | cols]

    prep_weights<<<128, 256, 0, stream>>>(We1, We2, Wh1, Wh2);
    pq_kernel<<<dim3((NN + 31) / 32, 2), 256, 0, stream>>>(h);
    hist_zero<<<196, 256, 0, stream>>>();
    hist_count<<<3125, 256, 0, stream>>>(eidx);
    scan1<<<196, 256, 0, stream>>>();
    scan2<<<1, 256, 0, stream>>>(196);
    scan3<<<196, 256, 0, stream>>>();
    csr_fill<<<3125, 256, 0, stream>>>(eidx);
    edge_agg<<<NN, 256, 0, stream>>>(x, ea, be1, be2, Wa, ba, eidx);
    node_kernel<<<(NN + NPB - 1) / NPB, 256, 0, stream>>>(h, bh1, bh2, (float*)d_out);
}

// Round 9
// 601.540 us; speedup vs baseline: 1.9728x; 1.3535x over previous
//
#include <hip/hip_runtime.h>
#include <hip/hip_bf16.h>

#define NN 50000
#define NE 800000
#define DH 128
#define DE 16
#define DM 128
#define K1 273
#define NPB 32
#define EPB 128   // sorted edges per block (4 tiles of 32)
#define M1S 136   // LDS row stride (bf16): 272B, 16B-aligned
#define NHS 264   // LDS row stride (bf16) for node h_in

typedef __attribute__((ext_vector_type(8))) short s16x8;
typedef __attribute__((ext_vector_type(4))) short s16x4;
typedef __attribute__((ext_vector_type(4))) float f32x4;

// Device-global scratch (no ws dependence). Fully rewritten every launch.
__device__ float g_msum[NN * DM];                    // 25.6 MB fp32
__device__ __hip_bfloat16 g_P[NN * DM];              // h @ W_a^T
__device__ __hip_bfloat16 g_Q[NN * DM];              // h @ W_b^T
__device__ __hip_bfloat16 g_W1a[128 * 128];
__device__ __hip_bfloat16 g_W1b[128 * 128];
__device__ __hip_bfloat16 g_Wes[128 * 32];           // [ea(16)|radial|pad] weights
__device__ __hip_bfloat16 g_W2b[128 * 128];
__device__ __hip_bfloat16 g_Wh1b[128 * 256];
__device__ __hip_bfloat16 g_Wh2b[128 * 128];
// CSR build
__device__ int g_hist[NN];
__device__ int g_off[NN];
__device__ int g_cur[NN];
__device__ int g_bsum[256];
__device__ int g_csr[NE];

__device__ __forceinline__ __hip_bfloat16 f2bf(float v) { return __float2bfloat16(v); }
__device__ __forceinline__ float bf2f(__hip_bfloat16 v) { return __bfloat162float(v); }
__device__ __forceinline__ short bfbits(float f) {
    __hip_bfloat16 b = __float2bfloat16(f);
    return *reinterpret_cast<short*>(&b);
}
__device__ __forceinline__ float b2f(short s) {
    unsigned u = ((unsigned)(unsigned short)s) << 16;
    float f; __builtin_memcpy(&f, &u, 4); return f;
}
__device__ __forceinline__ float silu(float v) { return v / (1.f + __expf(-v)); }

// zero msum (1.6M float4) + hist
__global__ __launch_bounds__(256) void zero_kernel() {
    int i = blockIdx.x * 256 + threadIdx.x;     // grid 6250
    if (i < NN * DM / 4) ((float4*)g_msum)[i] = make_float4(0.f, 0.f, 0.f, 0.f);
    if (i < NN) g_hist[i] = 0;
}

__global__ __launch_bounds__(256) void prep_weights(
    const float* __restrict__ We1, const float* __restrict__ We2,
    const float* __restrict__ Wh1, const float* __restrict__ Wh2) {
    int i = blockIdx.x * 256 + threadIdx.x;      // grid 128 -> 32768
    if (i < 16384) {
        int n = i >> 7, k = i & 127;
        g_W1a[i]  = f2bf(We1[n * K1 + k]);
        g_W1b[i]  = f2bf(We1[n * K1 + 128 + k]);
        g_W2b[i]  = f2bf(We2[i]);
        g_Wh2b[i] = f2bf(Wh2[i]);
    }
    if (i < 4096) {
        int n = i >> 5, k = i & 31;
        float v = (k < 16) ? We1[n * K1 + 257 + k] : (k == 16 ? We1[n * K1 + 256] : 0.f);
        g_Wes[i] = f2bf(v);
    }
    if (i < 32768) g_Wh1b[i] = f2bf(Wh1[i]);
}

// ---------- CSR build ----------
__global__ __launch_bounds__(256) void hist_count(const int* __restrict__ eidx) {
    int e = blockIdx.x * 256 + threadIdx.x;
    if (e < NE) atomicAdd(&g_hist[eidx[e]], 1);
}
__global__ __launch_bounds__(256) void scan1() {
    __shared__ int s[256];
    int tid = threadIdx.x, i = blockIdx.x * 256 + tid;
    int v = (i < NN) ? g_hist[i] : 0;
    s[tid] = v; __syncthreads();
    for (int o = 1; o < 256; o <<= 1) {
        int t = (tid >= o) ? s[tid - o] : 0;
        __syncthreads();
        s[tid] += t;
        __syncthreads();
    }
    if (i < NN) g_off[i] = s[tid] - v;
    if (tid == 255) g_bsum[blockIdx.x] = s[tid];
}
__global__ __launch_bounds__(256) void scan2(int nblk) {
    __shared__ int s[256];
    int tid = threadIdx.x;
    int v = (tid < nblk) ? g_bsum[tid] : 0;
    s[tid] = v; __syncthreads();
    for (int o = 1; o < 256; o <<= 1) {
        int t = (tid >= o) ? s[tid - o] : 0;
        __syncthreads();
        s[tid] += t;
        __syncthreads();
    }
    g_bsum[tid] = s[tid] - v;
}
__global__ __launch_bounds__(256) void scan3() {
    int i = blockIdx.x * 256 + threadIdx.x;
    if (i < NN) g_cur[i] = g_off[i] + g_bsum[blockIdx.x];
}
__global__ __launch_bounds__(256) void csr_fill(const int* __restrict__ eidx) {
    int e = blockIdx.x * 256 + threadIdx.x;
    if (e < NE) {
        int r = eidx[e];
        int pos = atomicAdd(&g_cur[r], 1);
        g_csr[pos] = e;
    }
}

// ---------- fused P/Q precompute: read h once, write both ----------
__global__ __launch_bounds__(256) void pq_kernel(const float* __restrict__ h) {
    __shared__ __align__(16) __hip_bfloat16 s_a[32 * M1S];
    const int tid = threadIdx.x, lane = tid & 63, wave = tid >> 6;
    const int n0 = blockIdx.x * 32;

    for (int i = tid; i < 32 * 16; i += 256) {
        int r = i >> 4, u = i & 15;
        int node = n0 + r; if (node >= NN) node = NN - 1;
        const float* hp = h + (size_t)node * DH + u * 8;
        float4 v0 = *(const float4*)(hp);
        float4 v1 = *(const float4*)(hp + 4);
        s16x8 t;
        t[0] = bfbits(v0.x); t[1] = bfbits(v0.y); t[2] = bfbits(v0.z); t[3] = bfbits(v0.w);
        t[4] = bfbits(v1.x); t[5] = bfbits(v1.y); t[6] = bfbits(v1.z); t[7] = bfbits(v1.w);
        *(s16x8*)(s_a + r * M1S + u * 8) = t;
    }
    __syncthreads();

    const int l15 = lane & 15, kq = (lane >> 4) * 8, rq = (lane >> 4) * 4, nb = wave * 32;
    #pragma unroll
    for (int w = 0; w < 2; w++) {
        const __hip_bfloat16* W = w ? g_W1b : g_W1a;
        __hip_bfloat16* out = w ? g_Q : g_P;
        f32x4 acc00 = {0,0,0,0}, acc01 = {0,0,0,0}, acc10 = {0,0,0,0}, acc11 = {0,0,0,0};
        #pragma unroll
        for (int k0 = 0; k0 < 128; k0 += 32) {
            s16x8 a0 = *(const s16x8*)(s_a + l15 * M1S + k0 + kq);
            s16x8 a1 = *(const s16x8*)(s_a + (16 + l15) * M1S + k0 + kq);
            s16x8 b0 = *(const s16x8*)(W + (size_t)(nb + l15) * 128 + k0 + kq);
            s16x8 b1 = *(const s16x8*)(W + (size_t)(nb + 16 + l15) * 128 + k0 + kq);
            acc00 = __builtin_amdgcn_mfma_f32_16x16x32_bf16(a0, b0, acc00, 0, 0, 0);
            acc01 = __builtin_amdgcn_mfma_f32_16x16x32_bf16(a0, b1, acc01, 0, 0, 0);
            acc10 = __builtin_amdgcn_mfma_f32_16x16x32_bf16(a1, b0, acc10, 0, 0, 0);
            acc11 = __builtin_amdgcn_mfma_f32_16x16x32_bf16(a1, b1, acc11, 0, 0, 0);
        }
        #pragma unroll
        for (int r = 0; r < 4; r++) {
            int m0 = n0 + rq + r, m1 = n0 + 16 + rq + r;
            if (m0 < NN) {
                out[(size_t)m0 * DM + nb + l15]      = f2bf(acc00[r]);
                out[(size_t)m0 * DM + nb + 16 + l15] = f2bf(acc01[r]);
            }
            if (m1 < NN) {
                out[(size_t)m1 * DM + nb + l15]      = f2bf(acc10[r]);
                out[(size_t)m1 * DM + nb + 16 + l15] = f2bf(acc11[r]);
            }
        }
    }
}

// ---------- sorted-edge-major kernel: 128 dest-sorted edges/block ----------
__global__ __launch_bounds__(256) void edge_sorted(
    const float* __restrict__ x,
    const float* __restrict__ ea,
    const float* __restrict__ be1,
    const float* __restrict__ be2,
    const float* __restrict__ Wa,
    const float* __restrict__ ba,
    const int* __restrict__ eidx)
{
    // LDS 30848 B -> 5 blocks/CU
    __shared__ __align__(16) char smem[30848];
    float* s_pre = (float*)smem;                            // [32][132] fp32; aliased s_out
    __hip_bfloat16* s_m1 = (__hip_bfloat16*)(smem + 16896); // [32][136] m1, then m2
    __hip_bfloat16* s_eain = (__hip_bfloat16*)(smem + 25600); // [32][32]
    float* s_part = (float*)(smem + 27648);                 // [8][32]
    float* s_att  = (float*)(smem + 28672);                 // [32]
    int*   s_dest = (int*)(smem + 28800);                   // [128]
    int*   s_col  = (int*)(smem + 29312);                   // [128]
    int*   s_eidv = (int*)(smem + 29824);                   // [128]
    float* s_rad  = (float*)(smem + 30336);                 // [128]

    const int tid  = threadIdx.x;
    const int lane = tid & 63;
    const int wave = tid >> 6;
    const int e0   = blockIdx.x * EPB;
    const int l15 = lane & 15;
    const int kq  = (lane >> 4) * 8;
    const int rq  = (lane >> 4) * 4;
    const int nb  = wave * 32;

    if (tid < EPB) {
        int eid = g_csr[e0 + tid];
        int dst = eidx[eid], col = eidx[NE + eid];
        s_eidv[tid] = eid; s_dest[tid] = dst; s_col[tid] = col;
        float dx = x[dst*3+0] - x[col*3+0];
        float dy = x[dst*3+1] - x[col*3+1];
        float dz = x[dst*3+2] - x[col*3+2];
        s_rad[tid] = sqrtf(dx*dx + dy*dy + dz*dz);
    }
    __syncthreads();

    // segmented-walk state (threads 0..127, uniform control flow)
    int cur = -1, runStart = 0;
    float acc = 0.f;

    for (int t = 0; t < 4; t++) {
        const int eb = t * 32;
        // gather P[dst]+Q[col] -> s_pre fp32
        {
            int el = tid >> 3, c = tid & 7;
            int dst = s_dest[eb + el], col = s_col[eb + el];
            s16x8 pb = *(const s16x8*)(g_P + (size_t)dst * DM + c * 16);
            s16x8 qb = *(const s16x8*)(g_Q + (size_t)col * DM + c * 16);
            float* dp = s_pre + el * 132 + c * 16;
            #pragma unroll
            for (int j = 0; j < 16; j++) dp[j] = b2f(pb[j]) + b2f(qb[j]);
        }
        // s_eain: [ea(16) | radial | zeros]
        for (int i = tid; i < 32 * 32; i += 256) {
            int el = i >> 5, k = i & 31;
            float v = (k < 16) ? ea[(size_t)s_eidv[eb + el] * DE + k]
                               : (k == 16 ? s_rad[eb + el] : 0.f);
            s_eain[i] = f2bf(v);
        }
        __syncthreads();

        // layer 1: m1 = silu(P+Q+be1 + [ea|rad]@Wes^T) -> s_m1
        {
            float b0v = be1[nb + l15], b1v = be1[nb + 16 + l15];
            f32x4 a00, a01, a10, a11;
            #pragma unroll
            for (int r = 0; r < 4; r++) {
                a00[r] = s_pre[(rq + r) * 132 + nb + l15] + b0v;
                a01[r] = s_pre[(rq + r) * 132 + nb + 16 + l15] + b1v;
                a10[r] = s_pre[(16 + rq + r) * 132 + nb + l15] + b0v;
                a11[r] = s_pre[(16 + rq + r) * 132 + nb + 16 + l15] + b1v;
            }
            s16x8 fa0 = *(const s16x8*)(s_eain + l15 * 32 + kq);
            s16x8 fa1 = *(const s16x8*)(s_eain + (16 + l15) * 32 + kq);
            s16x8 fb0 = *(const s16x8*)(g_Wes + (nb + l15) * 32 + kq);
            s16x8 fb1 = *(const s16x8*)(g_Wes + (nb + 16 + l15) * 32 + kq);
            a00 = __builtin_amdgcn_mfma_f32_16x16x32_bf16(fa0, fb0, a00, 0, 0, 0);
            a01 = __builtin_amdgcn_mfma_f32_16x16x32_bf16(fa0, fb1, a01, 0, 0, 0);
            a10 = __builtin_amdgcn_mfma_f32_16x16x32_bf16(fa1, fb0, a10, 0, 0, 0);
            a11 = __builtin_amdgcn_mfma_f32_16x16x32_bf16(fa1, fb1, a11, 0, 0, 0);
            #pragma unroll
            for (int r = 0; r < 4; r++) {
                s_m1[(rq + r) * M1S + nb + l15]           = f2bf(silu(a00[r]));
                s_m1[(rq + r) * M1S + nb + 16 + l15]      = f2bf(silu(a01[r]));
                s_m1[(16 + rq + r) * M1S + nb + l15]      = f2bf(silu(a10[r]));
                s_m1[(16 + rq + r) * M1S + nb + 16 + l15] = f2bf(silu(a11[r]));
            }
        }
        __syncthreads();

        // layer 2: m2 = silu(m1 @ We2^T + be2) -> registers
        float bias0 = be2[nb + l15];
        float bias1 = be2[nb + 16 + l15];
        f32x4 m00 = {bias0, bias0, bias0, bias0};
        f32x4 m01 = {bias1, bias1, bias1, bias1};
        f32x4 m10 = m00, m11 = m01;
        #pragma unroll
        for (int k0 = 0; k0 < 128; k0 += 32) {
            s16x8 a0 = *(const s16x8*)(s_m1 + l15 * M1S + k0 + kq);
            s16x8 a1 = *(const s16x8*)(s_m1 + (16 + l15) * M1S + k0 + kq);
            s16x8 b0 = *(const s16x8*)(g_W2b + (size_t)(nb + l15) * 128 + k0 + kq);
            s16x8 b1 = *(const s16x8*)(g_W2b + (size_t)(nb + 16 + l15) * 128 + k0 + kq);
            m00 = __builtin_amdgcn_mfma_f32_16x16x32_bf16(a0, b0, m00, 0, 0, 0);
            m01 = __builtin_amdgcn_mfma_f32_16x16x32_bf16(a0, b1, m01, 0, 0, 0);
            m10 = __builtin_amdgcn_mfma_f32_16x16x32_bf16(a1, b0, m10, 0, 0, 0);
            m11 = __builtin_amdgcn_mfma_f32_16x16x32_bf16(a1, b1, m11, 0, 0, 0);
        }
        #pragma unroll
        for (int r = 0; r < 4; r++) {
            m00[r] = silu(m00[r]); m01[r] = silu(m01[r]);
            m10[r] = silu(m10[r]); m11[r] = silu(m11[r]);
        }
        __syncthreads();        // everyone done reading s_m1 -> reuse for m2

        #pragma unroll
        for (int r = 0; r < 4; r++) {
            s_m1[(rq + r) * M1S + nb + l15]           = f2bf(m00[r]);
            s_m1[(rq + r) * M1S + nb + 16 + l15]      = f2bf(m01[r]);
            s_m1[(16 + rq + r) * M1S + nb + l15]      = f2bf(m10[r]);
            s_m1[(16 + rq + r) * M1S + nb + 16 + l15] = f2bf(m11[r]);
        }
        __syncthreads();

        // attention gate
        {
            int e = tid & 31, part = tid >> 5;
            float p = 0.f;
            #pragma unroll
            for (int j = 0; j < 16; j++) {
                int d = part * 16 + j;
                p += bf2f(s_m1[e * M1S + d]) * Wa[d];
            }
            s_part[part * 32 + e] = p;
        }
        __syncthreads();
        if (tid < 32) {
            float s = ba[0];
            #pragma unroll
            for (int p = 0; p < 8; p++) s += s_part[p * 32 + tid];
            s_att[tid] = 1.f / (1.f + __expf(-s));
        }
        __syncthreads();

        // s_out = m2 * att (fp32, aliases s_pre)
        #pragma unroll
        for (int r = 0; r < 4; r++) {
            float aL = s_att[rq + r], aH = s_att[16 + rq + r];
            s_pre[(rq + r) * 132 + nb + l15]           = m00[r] * aL;
            s_pre[(rq + r) * 132 + nb + 16 + l15]      = m01[r] * aL;
            s_pre[(16 + rq + r) * 132 + nb + l15]      = m10[r] * aH;
            s_pre[(16 + rq + r) * 132 + nb + 16 + l15] = m11[r] * aH;
        }
        __syncthreads();

        // segmented walk: thread d accumulates over sorted edges, flushes on dest change
        if (tid < 128) {
            int d = tid;
            for (int el = 0; el < 32; el++) {
                int i = eb + el;
                int dst = s_dest[i];
                if (dst != cur) {
                    if (cur >= 0) {
                        if (runStart == 0)   // run touches block start: boundary
                            atomicAdd(&g_msum[(size_t)cur * DM + d], acc);
                        else                 // strictly interior run: exclusive
                            g_msum[(size_t)cur * DM + d] = acc;
                    }
                    cur = dst; acc = 0.f; runStart = i;
                }
                acc += s_pre[el * 132 + d];
            }
        }
        __syncthreads();   // s_out consumed before next tile's gather
    }
    // final run ends at block edge 127: boundary
    if (tid < 128 && cur >= 0)
        atomicAdd(&g_msum[(size_t)cur * DM + tid], acc);
}

__global__ __launch_bounds__(256) void node_kernel(
    const float* __restrict__ h,
    const float* __restrict__ bh1,
    const float* __restrict__ bh2,
    float* __restrict__ out)
{
    __shared__ __align__(16) __hip_bfloat16 s_hin[NPB * NHS];
    __shared__ __align__(16) __hip_bfloat16 s_t[NPB * M1S];

    const int tid  = threadIdx.x;
    const int lane = tid & 63;
    const int wave = tid >> 6;
    const int n0   = blockIdx.x * NPB;

    for (int i = tid; i < 32 * 16; i += 256) {
        int r = i >> 4, u = i & 15;
        int node = n0 + r; if (node >= NN) node = NN - 1;
        const float* hp = h + (size_t)node * DH + u * 8;
        float4 v0 = *(const float4*)(hp);
        float4 v1 = *(const float4*)(hp + 4);
        s16x8 t;
        t[0] = bfbits(v0.x); t[1] = bfbits(v0.y); t[2] = bfbits(v0.z); t[3] = bfbits(v0.w);
        t[4] = bfbits(v1.x); t[5] = bfbits(v1.y); t[6] = bfbits(v1.z); t[7] = bfbits(v1.w);
        *(s16x8*)(s_hin + r * NHS + u * 8) = t;
    }
    for (int i = tid; i < 32 * 32; i += 256) {
        int r = i >> 5, u = i & 31;
        int node = n0 + r; if (node >= NN) node = NN - 1;
        float4 v = *(const float4*)(g_msum + (size_t)node * DM + u * 4);
        s16x4 t;
        t[0] = bfbits(v.x); t[1] = bfbits(v.y); t[2] = bfbits(v.z); t[3] = bfbits(v.w);
        *(s16x4*)(s_hin + r * NHS + 128 + u * 4) = t;
    }
    __syncthreads();

    const int l15 = lane & 15;
    const int kq  = (lane >> 4) * 8;
    const int rq  = (lane >> 4) * 4;
    const int nb  = wave * 32;

    {
        float bias0 = bh1[nb + l15];
        float bias1 = bh1[nb + 16 + l15];
        f32x4 acc00 = {bias0, bias0, bias0, bias0};
        f32x4 acc01 = {bias1, bias1, bias1, bias1};
        f32x4 acc10 = acc00, acc11 = acc01;
        #pragma unroll
        for (int k0 = 0; k0 < 256; k0 += 32) {
            s16x8 a0 = *(const s16x8*)(s_hin + l15 * NHS + k0 + kq);
            s16x8 a1 = *(const s16x8*)(s_hin + (16 + l15) * NHS + k0 + kq);
            s16x8 b0 = *(const s16x8*)(g_Wh1b + (size_t)(nb + l15) * 256 + k0 + kq);
            s16x8 b1 = *(const s16x8*)(g_Wh1b + (size_t)(nb + 16 + l15) * 256 + k0 + kq);
            acc00 = __builtin_amdgcn_mfma_f32_16x16x32_bf16(a0, b0, acc00, 0, 0, 0);
            acc01 = __builtin_amdgcn_mfma_f32_16x16x32_bf16(a0, b1, acc01, 0, 0, 0);
            acc10 = __builtin_amdgcn_mfma_f32_16x16x32_bf16(a1, b0, acc10, 0, 0, 0);
            acc11 = __builtin_amdgcn_mfma_f32_16x16x32_bf16(a1, b1, acc11, 0, 0, 0);
        }
        #pragma unroll
        for (int r = 0; r < 4; r++) {
            s_t[(rq + r) * M1S + nb + l15]           = f2bf(silu(acc00[r]));
            s_t[(rq + r) * M1S + nb + 16 + l15]      = f2bf(silu(acc01[r]));
            s_t[(16 + rq + r) * M1S + nb + l15]      = f2bf(silu(acc10[r]));
            s_t[(16 + rq + r) * M1S + nb + 16 + l15] = f2bf(silu(acc11[r]));
        }
    }
    __syncthreads();

    {
        float bias0 = bh2[nb + l15];
        float bias1 = bh2[nb + 16 + l15];
        f32x4 acc00 = {bias0, bias0, bias0, bias0};
        f32x4 acc01 = {bias1, bias1, bias1, bias1};
        f32x4 acc10 = acc00, acc11 = acc01;
        #pragma unroll
        for (int k0 = 0; k0 < 128; k0 += 32) {
            s16x8 a0 = *(const s16x8*)(s_t + l15 * M1S + k0 + kq);
            s16x8 a1 = *(const s16x8*)(s_t + (16 + l15) * M1S + k0 + kq);
            s16x8 b0 = *(const s16x8*)(g_Wh2b + (size_t)(nb + l15) * 128 + k0 + kq);
            s16x8 b1 = *(const s16x8*)(g_Wh2b + (size_t)(nb + 16 + l15) * 128 + k0 + kq);
            acc00 = __builtin_amdgcn_mfma_f32_16x16x32_bf16(a0, b0, acc00, 0, 0, 0);
            acc01 = __builtin_amdgcn_mfma_f32_16x16x32_bf16(a0, b1, acc01, 0, 0, 0);
            acc10 = __builtin_amdgcn_mfma_f32_16x16x32_bf16(a1, b0, acc10, 0, 0, 0);
            acc11 = __builtin_amdgcn_mfma_f32_16x16x32_bf16(a1, b1, acc11, 0, 0, 0);
        }
        #pragma unroll
        for (int r = 0; r < 4; r++) {
            int n00 = n0 + rq + r;
            int n16 = n0 + 16 + rq + r;
            int d0 = nb + l15, d1 = nb + 16 + l15;
            if (n00 < NN) {
                out[(size_t)n00 * DH + d0] = acc00[r] + h[(size_t)n00 * DH + d0];
                out[(size_t)n00 * DH + d1] = acc01[r] + h[(size_t)n00 * DH + d1];
            }
            if (n16 < NN) {
                out[(size_t)n16 * DH + d0] = acc10[r] + h[(size_t)n16 * DH + d0];
                out[(size_t)n16 * DH + d1] = acc11[r] + h[(size_t)n16 * DH + d1];
            }
        }
    }
}

extern "C" void kernel_launch(void* const* d_in, const int* in_sizes, int n_in,
                              void* d_out, int out_size, void* d_ws, size_t ws_size,
                              hipStream_t stream) {
    const float* x   = (const float*)d_in[0];
    const float* h   = (const float*)d_in[1];
    const float* ea  = (const float*)d_in[2];
    const float* We1 = (const float*)d_in[3];
    const float* be1 = (const float*)d_in[4];
    const float* We2 = (const float*)d_in[5];
    const float* be2 = (const float*)d_in[6];
    const float* Wh1 = (const float*)d_in[7];
    const float* bh1 = (const float*)d_in[8];
    const float* Wh2 = (const float*)d_in[9];
    const float* bh2 = (const float*)d_in[10];
    const float* Wa  = (const float*)d_in[11];
    const float* ba  = (const float*)d_in[12];
    const int* eidx  = (const int*)d_in[13];   // int32 planar [rows | cols]

    zero_kernel<<<6250, 256, 0, stream>>>();
    prep_weights<<<128, 256, 0, stream>>>(We1, We2, Wh1, Wh2);
    pq_kernel<<<(NN + 31) / 32, 256, 0, stream>>>(h);
    hist_count<<<3125, 256, 0, stream>>>(eidx);
    scan1<<<196, 256, 0, stream>>>();
    scan2<<<1, 256, 0, stream>>>(196);
    scan3<<<196, 256, 0, stream>>>();
    csr_fill<<<3125, 256, 0, stream>>>(eidx);
    edge_sorted<<<NE / EPB, 256, 0, stream>>>(x, ea, be1, be2, Wa, ba, eidx);
    node_kernel<<<(NN + NPB - 1) / NPB, 256, 0, stream>>>(h, bh1, bh2, (float*)d_out);
}